// Round 3
// baseline (907.330 us; speedup 1.0000x reference)
//
#include <hip/hip_runtime.h>
#include <math.h>

#define NN 131072            // total nodes
#define FF 32                // input features
#define EE 524288            // random edges
#define ET (EE + NN)         // edges + self loops = 655360
#define BB 2048              // batch (graphs)

// ---------------- wave reductions (wave64) ----------------
__device__ __forceinline__ float wave_sum(float v) {
  #pragma unroll
  for (int o = 32; o >= 1; o >>= 1) v += __shfl_xor(v, o);
  return v;
}
__device__ __forceinline__ float wave_max(float v) {
  #pragma unroll
  for (int o = 32; o >= 1; o >>= 1) v = fmaxf(v, __shfl_xor(v, o));
  return v;
}
// reductions within a 16-lane group (xor masks < 16 stay in-group)
__device__ __forceinline__ float g16_sum(float v) {
  #pragma unroll
  for (int o = 8; o >= 1; o >>= 1) v += __shfl_xor(v, o);
  return v;
}
__device__ __forceinline__ float g16_max(float v) {
  #pragma unroll
  for (int o = 8; o >= 1; o >>= 1) v = fmaxf(v, __shfl_xor(v, o));
  return v;
}

// ---------------- CSR build (counting sort by dst) ----------------
__global__ void init_counts(int* counts) {
  int i = blockIdx.x * 256 + threadIdx.x;
  counts[i] = 1;                       // self loop contributes 1 per node
}

__global__ void count_edges(const int* __restrict__ ei, int* counts) {
  int e = blockIdx.x * 256 + threadIdx.x;
  atomicAdd(&counts[ei[EE + e]], 1);   // dst row of edge_index
}

__global__ void scan_block(const int* __restrict__ counts, int* offs, int* blksums) {
  __shared__ int sd[256];
  int t = threadIdx.x;
  int i = blockIdx.x * 256 + t;
  int v = counts[i];
  sd[t] = v;
  __syncthreads();
  for (int o = 1; o < 256; o <<= 1) {
    int x = (t >= o) ? sd[t - o] : 0;
    __syncthreads();
    sd[t] += x;
    __syncthreads();
  }
  offs[i] = sd[t] - v;                 // block-local exclusive scan
  if (t == 255) blksums[blockIdx.x] = sd[255];
}

__global__ void scan_sums(int* blksums) {  // 1 block x 512 threads
  __shared__ int sd[512];
  int t = threadIdx.x;
  int v = blksums[t];
  sd[t] = v;
  __syncthreads();
  for (int o = 1; o < 512; o <<= 1) {
    int x = (t >= o) ? sd[t - o] : 0;
    __syncthreads();
    sd[t] += x;
    __syncthreads();
  }
  blksums[t] = sd[t] - v;              // exclusive scan of block sums
}

__global__ void scan_add(int* offs, int* cursor, const int* __restrict__ blksums) {
  int i = blockIdx.x * 256 + threadIdx.x;
  int o = offs[i] + blksums[blockIdx.x];
  offs[i] = o;
  cursor[i] = o;
  if (i == 0) offs[NN] = ET;
}

__global__ void fill_csr(const int* __restrict__ ei, int* cursor, int* esrc) {
  int i = blockIdx.x * 256 + threadIdx.x;   // i < ET
  int s, d;
  if (i < EE) { s = ei[i]; d = ei[EE + i]; }
  else        { s = d = i - EE; }           // self loop
  int pos = atomicAdd(&cursor[d], 1);
  esrc[pos] = s;
}

// ---------------- layer-1 attention vectors: wts[h,k] = sum_c W1[k,h*64+c]*a1s[h,c]
__global__ void l1_avec(const float* __restrict__ W1, const float* __restrict__ a1s,
                        const float* __restrict__ a1d, float* __restrict__ wts,
                        float* __restrict__ wtd) {
  int t = threadIdx.x;          // 128 threads: h = t>>5, k = t&31
  int h = t >> 5, k = t & 31;
  float as = 0.f, ad = 0.f;
  #pragma unroll
  for (int c = 0; c < 64; ++c) {
    float w = W1[k * 256 + h * 64 + c];
    as += w * a1s[h * 64 + c];
    ad += w * a1d[h * 64 + c];
  }
  wts[t] = as;
  wtd[t] = ad;
}

// ---------------- layer-1 logits: als[n,h] = x[n]·wts[h]  (64 nodes / block)
__global__ __launch_bounds__(256) void l1_logits(
    const float* __restrict__ x, const float* __restrict__ wts,
    const float* __restrict__ wtd, float* __restrict__ als, float* __restrict__ ald) {
  __shared__ float sx[64 * 33];     // padded stride 33: kill bank conflicts
  __shared__ float sts[128], std_[128];
  int t = threadIdx.x;
  int n0 = blockIdx.x * 64;
  #pragma unroll
  for (int j = 0; j < 8; ++j) {
    int idx = t + j * 256;          // 0..2047
    sx[(idx >> 5) * 33 + (idx & 31)] = x[(size_t)n0 * 32 + idx];
  }
  if (t < 128) sts[t] = wts[t]; else std_[t - 128] = wtd[t - 128];
  __syncthreads();
  int nl = t >> 2, h = t & 3;       // 64 nodes x 4 heads
  float vs = 0.f, vd = 0.f;
  #pragma unroll
  for (int k = 0; k < 32; ++k) {
    float xv = sx[nl * 33 + k];
    vs += xv * sts[h * 32 + k];
    vd += xv * std_[h * 32 + k];
  }
  als[(n0 + nl) * 4 + h] = vs;
  ald[(n0 + nl) * 4 + h] = vd;
}

// ---------------- fused GAT1: x-space online-softmax aggregate + W1 GEMM + bias + relu
// 4 waves/block, wave handles 4 nodes; lane = (h = lane>>4, le = lane&15).
// Per 16-edge chunk: alpha via als4 gathers (lanes = edge x head), then
// xa[h][k] accumulation gathering x[src] (32 floats, shared across heads via L1).
// Epilogue: agg1[n, h*64+c] = relu( xa[h]·W1[:,h*64+c] + b1 ).
__global__ __launch_bounds__(256) void gat1_fused(
    const float* __restrict__ x, const float* __restrict__ als,
    const float* __restrict__ ald, const int* __restrict__ offs,
    const int* __restrict__ esrc, const float* __restrict__ W1,
    const float* __restrict__ b1, float* __restrict__ agg1) {
  __shared__ float sW1[32 * 256];   // 32 KB, whole W1
  __shared__ int   lsrc[4][16];
  __shared__ float lpp[4][64];      // [wave][h*16+le]
  __shared__ float sxa[4][128];     // [wave][h*32+k]
  int t = threadIdx.x;
  #pragma unroll
  for (int j = 0; j < 32; ++j) sW1[t + j * 256] = W1[t + j * 256];
  __syncthreads();
  int wv = t >> 6, lane = t & 63, h = lane >> 4, le = lane & 15;
  for (int i = 0; i < 4; ++i) {
    int n = blockIdx.x * 16 + wv * 4 + i;
    int start = offs[n], end = offs[n + 1];
    float aldn = ald[n * 4 + h];
    float M = -INFINITY, S = 0.f, xa0 = 0.f, xa1 = 0.f;
    for (int j0 = start; j0 < end; j0 += 16) {
      int cnt = end - j0; if (cnt > 16) cnt = 16;
      int s = (le < cnt) ? esrc[j0 + le] : 0;
      if (h == 0) lsrc[wv][le] = s;
      float e = -INFINITY;
      if (le < cnt) {
        e = als[s * 4 + h] + aldn;
        e = (e > 0.f) ? e : 0.2f * e;           // leaky relu
      }
      float Mn = fmaxf(M, g16_max(e));          // cnt>=1 (self loop) => finite
      float scale = __expf(M - Mn);             // first chunk: exp(-inf)=0
      float p = (le < cnt) ? __expf(e - Mn) : 0.f;
      S = S * scale + g16_sum(p);
      xa0 *= scale; xa1 *= scale;
      lpp[wv][h * 16 + le] = p;                 // wave-local LDS: no barrier
      for (int j = 0; j < cnt; ++j) {
        float pj = lpp[wv][h * 16 + j];
        int sj = lsrc[wv][j];
        xa0 += pj * x[(size_t)sj * 32 + le];
        xa1 += pj * x[(size_t)sj * 32 + 16 + le];
      }
      M = Mn;
    }
    float inv = 1.0f / (S + 1e-16f);
    sxa[wv][h * 32 + le] = xa0 * inv;
    sxa[wv][h * 32 + 16 + le] = xa1 * inv;      // wave-local: no barrier
    #pragma unroll
    for (int hh = 0; hh < 4; ++hh) {
      float acc = b1[hh * 64 + lane];
      #pragma unroll
      for (int k = 0; k < 32; ++k)
        acc += sxa[wv][hh * 32 + k] * sW1[k * 256 + hh * 64 + lane];
      agg1[(size_t)n * 256 + hh * 64 + lane] = fmaxf(acc, 0.f);
    }
  }
}

// ---------------- generic GEMM: A[M,K] @ W[K,64] (+bias+relu | +al epilogue)
template <int KTILES, int ROWS, bool AL>
__global__ __launch_bounds__(256) void gemm_n64(
    const float* __restrict__ A, const float* __restrict__ W,
    const float* __restrict__ bias, const float* __restrict__ a_s,
    const float* __restrict__ a_d, float* __restrict__ out,
    float* __restrict__ als, float* __restrict__ ald) {
  constexpr int K = KTILES * 64;
  constexpr int RPW = ROWS / 4;
  __shared__ float sW[64 * 64];       // 16 KB
  __shared__ float sA[ROWS * 64];
  int t = threadIdx.x;
  int c = t & 63;
  int rs = t >> 6;
  int row0 = blockIdx.x * ROWS;
  float acc[RPW];
  #pragma unroll
  for (int i = 0; i < RPW; ++i) acc[i] = 0.f;
  for (int kt = 0; kt < KTILES; ++kt) {
    #pragma unroll
    for (int j = 0; j < 16; ++j) sW[t + j * 256] = W[kt * 4096 + t + j * 256];
    #pragma unroll
    for (int j = 0; j < ROWS * 64 / 256; ++j) {
      int li = t + j * 256;
      int r = li >> 6, kk = li & 63;
      sA[li] = A[(size_t)(row0 + r) * K + kt * 64 + kk];
    }
    __syncthreads();
    #pragma unroll
    for (int rr = 0; rr < RPW; ++rr) {
      int r = rs * RPW + rr;
      float a0 = acc[rr];
      #pragma unroll
      for (int kk = 0; kk < 64; ++kk) a0 += sA[r * 64 + kk] * sW[kk * 64 + c];
      acc[rr] = a0;
    }
    __syncthreads();
  }
  #pragma unroll
  for (int rr = 0; rr < RPW; ++rr) {
    int r = row0 + rs * RPW + rr;
    if constexpr (AL) {
      out[(size_t)r * 64 + c] = acc[rr];       // raw h (bias comes in aggregate)
      float vs = wave_sum(acc[rr] * a_s[c]);
      float vd = wave_sum(acc[rr] * a_d[c]);
      if (c == 0) { als[r] = vs; ald[r] = vd; }
    } else {
      float v = acc[rr] + bias[c];
      out[(size_t)r * 64 + c] = fmaxf(v, 0.f); // fc1: bias + relu
    }
  }
}

// ---------------- H=1 single-pass online-softmax aggregate + bias + relu
__global__ __launch_bounds__(256) void gat_aggregate(
    const float* __restrict__ hsrc, const float* __restrict__ als,
    const float* __restrict__ ald, const int* __restrict__ offs,
    const int* __restrict__ esrc, const float* __restrict__ bias,
    float* __restrict__ out) {
  int wv = threadIdx.x >> 6;
  int lane = threadIdx.x & 63;
  int n = blockIdx.x * 4 + wv;
  __shared__ float lp[4][64];
  __shared__ int   lsrc[4][64];
  int start = offs[n], end = offs[n + 1];
  float aldn = ald[n];
  float M = -INFINITY, S = 0.f, acc = 0.f;
  for (int j0 = start; j0 < end; j0 += 64) {
    int cnt = end - j0; if (cnt > 64) cnt = 64;
    int s = 0; float e = -INFINITY;
    if (lane < cnt) {
      s = esrc[j0 + lane];
      e = als[s] + aldn;
      e = (e > 0.f) ? e : 0.2f * e;               // leaky relu
    }
    float Mn = fmaxf(M, wave_max(e));             // self-loop => cnt>=1
    float scale = __expf(M - Mn);                 // first chunk: exp(-inf)=0
    float p = (lane < cnt) ? __expf(e - Mn) : 0.f;
    S = S * scale + wave_sum(p);
    acc *= scale;
    lp[wv][lane] = p;
    lsrc[wv][lane] = s;                           // wave-local LDS: no barrier
    for (int j = 0; j < cnt; ++j) {               // lanes = channels, 256B coalesced
      acc += lp[wv][j] * hsrc[(size_t)lsrc[wv][j] * 64 + lane];
    }
    M = Mn;
  }
  float v = acc / (S + 1e-16f) + bias[lane];
  out[(size_t)n * 64 + lane] = fmaxf(v, 0.f);     // all layers relu'd
}

// ---------------- fc2 + fc3 + softmax, one wave per batch row ----------------
__global__ __launch_bounds__(256) void fc23_softmax(
    const float* __restrict__ h1, const float* __restrict__ W2,
    const float* __restrict__ b2, const float* __restrict__ W3,
    const float* __restrict__ b3, float* __restrict__ out) {
  int ws = threadIdx.x >> 6;
  int row = blockIdx.x * 4 + ws;
  int lane = threadIdx.x & 63;
  __shared__ float sh2[4][32];
  if (lane < 32) {
    float acc = b2[lane];
    for (int k = 0; k < 64; ++k) acc += h1[row * 64 + k] * W2[k * 32 + lane];
    sh2[ws][lane] = fmaxf(acc, 0.f);
  }
  __syncthreads();
  float logit = -INFINITY;
  if (lane < 16) {
    float acc = b3[lane];
    for (int k = 0; k < 32; ++k) acc += sh2[ws][k] * W3[k * 16 + lane];
    logit = acc;
  }
  float mx = logit;
  #pragma unroll
  for (int o = 8; o >= 1; o >>= 1) mx = fmaxf(mx, __shfl_xor(mx, o));
  float ex = (lane < 16) ? __expf(logit - mx) : 0.f;
  float ssum = ex;
  #pragma unroll
  for (int o = 8; o >= 1; o >>= 1) ssum += __shfl_xor(ssum, o);
  if (lane < 16) out[row * 16 + lane] = ex / ssum;
}

// ---------------- launcher ----------------
extern "C" void kernel_launch(void* const* d_in, const int* in_sizes, int n_in,
                              void* d_out, int out_size, void* d_ws, size_t ws_size,
                              hipStream_t stream) {
  const float* x0   = (const float*)d_in[0];
  const int*   ei   = (const int*)d_in[1];
  const float* W1   = (const float*)d_in[2];
  const float* a1s  = (const float*)d_in[3];
  const float* a1d  = (const float*)d_in[4];
  const float* b1   = (const float*)d_in[5];
  const float* W2   = (const float*)d_in[6];
  const float* a2s  = (const float*)d_in[7];
  const float* a2d  = (const float*)d_in[8];
  const float* b2   = (const float*)d_in[9];
  const float* W3   = (const float*)d_in[10];
  const float* a3s  = (const float*)d_in[11];
  const float* a3d  = (const float*)d_in[12];
  const float* b3   = (const float*)d_in[13];
  const float* fcW1 = (const float*)d_in[14];
  const float* fcb1 = (const float*)d_in[15];
  const float* fcW2 = (const float*)d_in[16];
  const float* fcb2 = (const float*)d_in[17];
  const float* fcW3 = (const float*)d_in[18];
  const float* fcb3 = (const float*)d_in[19];
  float* out = (float*)d_out;

  // workspace layout (~210 MB total)
  float* agg1   = (float*)d_ws;                       // [N*256] 134 MB
  float* h23    = agg1 + (size_t)NN * 256;            // [N*64]  (h2 then h3)
  float* agg23  = h23 + (size_t)NN * 64;              // [N*64]  (agg2 then agg3)
  float* als    = agg23 + (size_t)NN * 64;            // [N*4]
  float* ald    = als + (size_t)NN * 4;               // [N*4]
  float* hfc1   = ald + (size_t)NN * 4;               // [B*64]
  float* wts    = hfc1 + (size_t)BB * 64;             // [128]
  float* wtd    = wts + 128;                          // [128]
  int*   counts = (int*)(wtd + 128);                  // [N]
  int*   offs   = counts + NN;                        // [N+1]
  int*   cursor = offs + NN + 1;                      // [N]
  int*   esrc   = cursor + NN;                        // [ET]
  int*   blksums= esrc + ET;                          // [512]

  // CSR build (reused by all 3 GAT layers)
  init_counts<<<NN / 256, 256, 0, stream>>>(counts);
  count_edges<<<EE / 256, 256, 0, stream>>>(ei, counts);
  scan_block<<<NN / 256, 256, 0, stream>>>(counts, offs, blksums);
  scan_sums<<<1, 512, 0, stream>>>(blksums);
  scan_add<<<NN / 256, 256, 0, stream>>>(offs, cursor, blksums);
  fill_csr<<<ET / 256, 256, 0, stream>>>(ei, cursor, esrc);

  // GAT1 in x-space: logits from tiny projections, aggregate x, then W1
  l1_avec<<<1, 128, 0, stream>>>(W1, a1s, a1d, wts, wtd);
  l1_logits<<<NN / 64, 256, 0, stream>>>(x0, wts, wtd, als, ald);
  gat1_fused<<<NN / 16, 256, 0, stream>>>(x0, als, ald, offs, esrc, W1, b1, agg1);
  // GAT2: 256 -> 64
  gemm_n64<4, 32, true><<<NN / 32, 256, 0, stream>>>(agg1, W2, nullptr, a2s, a2d, h23, als, ald);
  gat_aggregate<<<NN / 4, 256, 0, stream>>>(h23, als, ald, offs, esrc, b2, agg23);
  // GAT3: 64 -> 64
  gemm_n64<1, 32, true><<<NN / 32, 256, 0, stream>>>(agg23, W3, nullptr, a3s, a3d, h23, als, ald);
  gat_aggregate<<<NN / 4, 256, 0, stream>>>(h23, als, ald, offs, esrc, b3, agg23);
  // actor MLP
  gemm_n64<64, 8, false><<<BB / 8, 256, 0, stream>>>(agg23, fcW1, fcb1, nullptr, nullptr, hfc1, nullptr, nullptr);
  fc23_softmax<<<BB / 4, 256, 0, stream>>>(hfc1, fcW2, fcb2, fcW3, fcb3, out);
}

// Round 5
// 696.812 us; speedup vs baseline: 1.3021x; 1.3021x over previous
//
#include <hip/hip_runtime.h>
#include <math.h>

#define NN 131072            // total nodes
#define FF 32                // input features
#define EE 524288            // random edges
#define ET (EE + NN)         // edges + self loops = 655360
#define BB 2048              // batch (graphs)

// ---------------- wave reductions (wave64) ----------------
__device__ __forceinline__ float wave_sum(float v) {
  #pragma unroll
  for (int o = 32; o >= 1; o >>= 1) v += __shfl_xor(v, o);
  return v;
}
__device__ __forceinline__ float wave_max(float v) {
  #pragma unroll
  for (int o = 32; o >= 1; o >>= 1) v = fmaxf(v, __shfl_xor(v, o));
  return v;
}
// reductions within a 16-lane group (xor masks < 16 stay in-group)
__device__ __forceinline__ float g16_sum(float v) {
  #pragma unroll
  for (int o = 8; o >= 1; o >>= 1) v += __shfl_xor(v, o);
  return v;
}
__device__ __forceinline__ float g16_max(float v) {
  #pragma unroll
  for (int o = 8; o >= 1; o >>= 1) v = fmaxf(v, __shfl_xor(v, o));
  return v;
}

// ---------------- CSR build (counting sort by dst) ----------------
__global__ void init_counts(int* counts) {
  int i = blockIdx.x * 256 + threadIdx.x;
  counts[i] = 1;                       // self loop contributes 1 per node
}

__global__ void count_edges(const int* __restrict__ ei, int* counts) {
  int e = blockIdx.x * 256 + threadIdx.x;
  atomicAdd(&counts[ei[EE + e]], 1);   // dst row of edge_index
}

__global__ void scan_block(const int* __restrict__ counts, int* offs, int* blksums) {
  __shared__ int sd[256];
  int t = threadIdx.x;
  int i = blockIdx.x * 256 + t;
  int v = counts[i];
  sd[t] = v;
  __syncthreads();
  for (int o = 1; o < 256; o <<= 1) {
    int x = (t >= o) ? sd[t - o] : 0;
    __syncthreads();
    sd[t] += x;
    __syncthreads();
  }
  offs[i] = sd[t] - v;                 // block-local exclusive scan
  if (t == 255) blksums[blockIdx.x] = sd[255];
}

__global__ void scan_sums(int* blksums) {  // 1 block x 512 threads
  __shared__ int sd[512];
  int t = threadIdx.x;
  int v = blksums[t];
  sd[t] = v;
  __syncthreads();
  for (int o = 1; o < 512; o <<= 1) {
    int x = (t >= o) ? sd[t - o] : 0;
    __syncthreads();
    sd[t] += x;
    __syncthreads();
  }
  blksums[t] = sd[t] - v;              // exclusive scan of block sums
}

__global__ void scan_add(int* offs, int* cursor, const int* __restrict__ blksums) {
  int i = blockIdx.x * 256 + threadIdx.x;
  int o = offs[i] + blksums[blockIdx.x];
  offs[i] = o;
  cursor[i] = o;
  if (i == 0) offs[NN] = ET;
}

__global__ void fill_csr(const int* __restrict__ ei, int* cursor, int* esrc) {
  int i = blockIdx.x * 256 + threadIdx.x;   // i < ET
  int s, d;
  if (i < EE) { s = ei[i]; d = ei[EE + i]; }
  else        { s = d = i - EE; }           // self loop
  int pos = atomicAdd(&cursor[d], 1);
  esrc[pos] = s;
}

// ---------------- layer-1 attention vectors: wts[h,k] = sum_c W1[k,h*64+c]*a1s[h,c]
__global__ void l1_avec(const float* __restrict__ W1, const float* __restrict__ a1s,
                        const float* __restrict__ a1d, float* __restrict__ wts,
                        float* __restrict__ wtd) {
  int t = threadIdx.x;          // 128 threads: h = t>>5, k = t&31
  int h = t >> 5, k = t & 31;
  float as = 0.f, ad = 0.f;
  #pragma unroll
  for (int c = 0; c < 64; ++c) {
    float w = W1[k * 256 + h * 64 + c];
    as += w * a1s[h * 64 + c];
    ad += w * a1d[h * 64 + c];
  }
  wts[t] = as;
  wtd[t] = ad;
}

// ---------------- layer-1 logits: als[n,h] = x[n]·wts[h]  (64 nodes / block)
__global__ __launch_bounds__(256) void l1_logits(
    const float* __restrict__ x, const float* __restrict__ wts,
    const float* __restrict__ wtd, float* __restrict__ als, float* __restrict__ ald) {
  __shared__ float sx[64 * 33];     // padded stride 33: kill bank conflicts
  __shared__ float sts[128], std_[128];
  int t = threadIdx.x;
  int n0 = blockIdx.x * 64;
  #pragma unroll
  for (int j = 0; j < 8; ++j) {
    int idx = t + j * 256;          // 0..2047
    sx[(idx >> 5) * 33 + (idx & 31)] = x[(size_t)n0 * 32 + idx];
  }
  if (t < 128) sts[t] = wts[t]; else std_[t - 128] = wtd[t - 128];
  __syncthreads();
  int nl = t >> 2, h = t & 3;       // 64 nodes x 4 heads
  float vs = 0.f, vd = 0.f;
  #pragma unroll
  for (int k = 0; k < 32; ++k) {
    float xv = sx[nl * 33 + k];
    vs += xv * sts[h * 32 + k];
    vd += xv * std_[h * 32 + k];
  }
  als[(n0 + nl) * 4 + h] = vs;
  ald[(n0 + nl) * 4 + h] = vd;
}

// ---------------- fused GAT1: x-space online-softmax aggregate + W1 GEMM + bias + relu
__global__ __launch_bounds__(256) void gat1_fused(
    const float* __restrict__ x, const float* __restrict__ als,
    const float* __restrict__ ald, const int* __restrict__ offs,
    const int* __restrict__ esrc, const float* __restrict__ W1,
    const float* __restrict__ b1, float* __restrict__ agg1) {
  __shared__ float sW1[32 * 256];   // 32 KB, whole W1
  __shared__ int   lsrc[4][16];
  __shared__ float lpp[4][64];      // [wave][h*16+le]
  __shared__ float sxa[4][128];     // [wave][h*32+k]
  int t = threadIdx.x;
  #pragma unroll
  for (int j = 0; j < 32; ++j) sW1[t + j * 256] = W1[t + j * 256];
  __syncthreads();
  int wv = t >> 6, lane = t & 63, h = lane >> 4, le = lane & 15;
  for (int i = 0; i < 4; ++i) {
    int n = blockIdx.x * 16 + wv * 4 + i;
    int start = offs[n], end = offs[n + 1];
    float aldn = ald[n * 4 + h];
    float M = -INFINITY, S = 0.f, xa0 = 0.f, xa1 = 0.f;
    for (int j0 = start; j0 < end; j0 += 16) {
      int cnt = end - j0; if (cnt > 16) cnt = 16;
      int s = (le < cnt) ? esrc[j0 + le] : 0;
      if (h == 0) lsrc[wv][le] = s;
      float e = -INFINITY;
      if (le < cnt) {
        e = als[s * 4 + h] + aldn;
        e = (e > 0.f) ? e : 0.2f * e;           // leaky relu
      }
      float Mn = fmaxf(M, g16_max(e));          // cnt>=1 (self loop) => finite
      float scale = __expf(M - Mn);             // first chunk: exp(-inf)=0
      float p = (le < cnt) ? __expf(e - Mn) : 0.f;
      S = S * scale + g16_sum(p);
      xa0 *= scale; xa1 *= scale;
      lpp[wv][h * 16 + le] = p;                 // wave-local LDS: no barrier
      for (int j = 0; j < cnt; ++j) {
        float pj = lpp[wv][h * 16 + j];
        int sj = lsrc[wv][j];
        xa0 += pj * x[(size_t)sj * 32 + le];
        xa1 += pj * x[(size_t)sj * 32 + 16 + le];
      }
      M = Mn;
    }
    float inv = 1.0f / (S + 1e-16f);
    sxa[wv][h * 32 + le] = xa0 * inv;
    sxa[wv][h * 32 + 16 + le] = xa1 * inv;      // wave-local: no barrier
    #pragma unroll
    for (int hh = 0; hh < 4; ++hh) {
      float acc = b1[hh * 64 + lane];
      #pragma unroll
      for (int k = 0; k < 32; ++k)
        acc += sxa[wv][hh * 32 + k] * sW1[k * 256 + hh * 64 + lane];
      agg1[(size_t)n * 256 + hh * 64 + lane] = fmaxf(acc, 0.f);
    }
  }
}

// ---------------- float4 register-tiled GEMM: A[M,K] @ W[K,64]
// thread = (row slot rs = t>>4, col quad cq = t&15); RPT rows/thread.
// Inner: float4 A broadcast + float4 W (lane-consecutive) -> 16 FMA per 5 LDS b128.
template <int KTILES, int ROWS, bool AL>
__global__ __launch_bounds__(256) void gemm_n64(
    const float* __restrict__ A, const float* __restrict__ W,
    const float* __restrict__ bias, const float* __restrict__ a_s,
    const float* __restrict__ a_d, float* __restrict__ out,
    float* __restrict__ als, float* __restrict__ ald) {
  constexpr int K = KTILES * 64;
  constexpr int RPT = ROWS / 16;       // rows per thread
  constexpr int SAS = 68;              // sA stride: 16B-aligned, bank-staggered
  __shared__ float sW[64 * 64];        // [k][c] 16 KB
  __shared__ float sA[ROWS * SAS];
  int t = threadIdx.x;
  int cq = t & 15;
  int rs = t >> 4;
  int row0 = blockIdx.x * ROWS;
  float4 acc[RPT];
  #pragma unroll
  for (int rp = 0; rp < RPT; ++rp) acc[rp] = make_float4(0.f, 0.f, 0.f, 0.f);
  for (int kt = 0; kt < KTILES; ++kt) {
    #pragma unroll
    for (int j = 0; j < 4; ++j) {      // stage W tile [64][64]
      int li = t + j * 256;
      int kk = li >> 4, cc = (li & 15) * 4;
      *(float4*)&sW[kk * 64 + cc] =
          *(const float4*)&W[(size_t)(kt * 64 + kk) * 64 + cc];
    }
    #pragma unroll
    for (int j = 0; j < ROWS / 16; ++j) {  // stage A tile [ROWS][64]
      int li = t + j * 256;
      int r = li >> 4, kkq = (li & 15) * 4;
      *(float4*)&sA[r * SAS + kkq] =
          *(const float4*)&A[(size_t)(row0 + r) * K + kt * 64 + kkq];
    }
    __syncthreads();
    #pragma unroll
    for (int kq = 0; kq < 16; ++kq) {
      float4 a4[RPT];
      #pragma unroll
      for (int rp = 0; rp < RPT; ++rp)
        a4[rp] = *(const float4*)&sA[(rs * RPT + rp) * SAS + kq * 4];
      #pragma unroll
      for (int i = 0; i < 4; ++i) {
        float4 w4 = *(const float4*)&sW[(kq * 4 + i) * 64 + cq * 4];
        #pragma unroll
        for (int rp = 0; rp < RPT; ++rp) {
          float a = (i == 0) ? a4[rp].x : (i == 1) ? a4[rp].y
                  : (i == 2) ? a4[rp].z : a4[rp].w;
          acc[rp].x += a * w4.x; acc[rp].y += a * w4.y;
          acc[rp].z += a * w4.z; acc[rp].w += a * w4.w;
        }
      }
    }
    __syncthreads();
  }
  #pragma unroll
  for (int rp = 0; rp < RPT; ++rp) {
    int r = row0 + rs * RPT + rp;
    if constexpr (AL) {
      *(float4*)&out[(size_t)r * 64 + cq * 4] = acc[rp];   // raw h
      float4 s4 = *(const float4*)&a_s[cq * 4];
      float4 d4 = *(const float4*)&a_d[cq * 4];
      float vs = acc[rp].x * s4.x + acc[rp].y * s4.y + acc[rp].z * s4.z + acc[rp].w * s4.w;
      float vd = acc[rp].x * d4.x + acc[rp].y * d4.y + acc[rp].z * d4.z + acc[rp].w * d4.w;
      #pragma unroll
      for (int o = 8; o >= 1; o >>= 1) { vs += __shfl_xor(vs, o); vd += __shfl_xor(vd, o); }
      if (cq == 0) { als[r] = vs; ald[r] = vd; }
    } else {
      float4 b4 = *(const float4*)&bias[cq * 4];
      float4 v = acc[rp];
      v.x = fmaxf(v.x + b4.x, 0.f); v.y = fmaxf(v.y + b4.y, 0.f);
      v.z = fmaxf(v.z + b4.z, 0.f); v.w = fmaxf(v.w + b4.w, 0.f);
      *(float4*)&out[(size_t)r * 64 + cq * 4] = v;
    }
  }
}

// ---------------- layer-2 aggregate fused with W3 GEMM + als3/ald3 epilogue
// out: h3 (raw), als3, ald3. One wave per dst node.
__global__ __launch_bounds__(256) void gat_agg_w3(
    const float* __restrict__ hsrc, const float* __restrict__ als,
    const float* __restrict__ ald, const int* __restrict__ offs,
    const int* __restrict__ esrc, const float* __restrict__ bias,
    const float* __restrict__ W3, const float* __restrict__ a3s,
    const float* __restrict__ a3d, float* __restrict__ hout,
    float* __restrict__ als3, float* __restrict__ ald3) {
  __shared__ float sW3[64 * 64];   // 16 KB
  __shared__ float lp[4][64];
  __shared__ int   lsrc[4][64];
  __shared__ float srow[4][64];
  int t = threadIdx.x;
  #pragma unroll
  for (int j = 0; j < 4; ++j) {
    int li = t + j * 256;
    int kk = li >> 4, cc = (li & 15) * 4;
    *(float4*)&sW3[kk * 64 + cc] = *(const float4*)&W3[kk * 64 + cc];
  }
  __syncthreads();
  int wv = t >> 6, lane = t & 63;
  int n = blockIdx.x * 4 + wv;
  int start = offs[n], end = offs[n + 1];
  float aldn = ald[n];
  float M = -INFINITY, S = 0.f, acc = 0.f;
  for (int j0 = start; j0 < end; j0 += 64) {
    int cnt = end - j0; if (cnt > 64) cnt = 64;
    int s = 0; float e = -INFINITY;
    if (lane < cnt) {
      s = esrc[j0 + lane];
      e = als[s] + aldn;
      e = (e > 0.f) ? e : 0.2f * e;               // leaky relu
    }
    float Mn = fmaxf(M, wave_max(e));             // self-loop => cnt>=1
    float scale = __expf(M - Mn);                 // first chunk: exp(-inf)=0
    float p = (lane < cnt) ? __expf(e - Mn) : 0.f;
    S = S * scale + wave_sum(p);
    acc *= scale;
    lp[wv][lane] = p;
    lsrc[wv][lane] = s;                           // wave-local LDS: no barrier
    for (int j = 0; j < cnt; ++j) {               // lanes = channels, 256B coalesced
      acc += lp[wv][j] * hsrc[(size_t)lsrc[wv][j] * 64 + lane];
    }
    M = Mn;
  }
  float v = acc / (S + 1e-16f) + bias[lane];
  v = fmaxf(v, 0.f);                              // agg2 (relu'd) value, k = lane
  srow[wv][lane] = v;                             // wave-local: no barrier
  float h3 = 0.f;
  #pragma unroll
  for (int kq = 0; kq < 16; ++kq) {               // h3 = srow @ W3
    float4 a4 = *(const float4*)&srow[wv][kq * 4];  // broadcast b128
    h3 += a4.x * sW3[(kq * 4 + 0) * 64 + lane];
    h3 += a4.y * sW3[(kq * 4 + 1) * 64 + lane];
    h3 += a4.z * sW3[(kq * 4 + 2) * 64 + lane];
    h3 += a4.w * sW3[(kq * 4 + 3) * 64 + lane];
  }
  float vs = wave_sum(h3 * a3s[lane]);
  float vd = wave_sum(h3 * a3d[lane]);
  if (lane == 0) { als3[n] = vs; ald3[n] = vd; }
  hout[(size_t)n * 64 + lane] = h3;               // raw h3
}

// ---------------- H=1 single-pass online-softmax aggregate + bias + relu
__global__ __launch_bounds__(256) void gat_aggregate(
    const float* __restrict__ hsrc, const float* __restrict__ als,
    const float* __restrict__ ald, const int* __restrict__ offs,
    const int* __restrict__ esrc, const float* __restrict__ bias,
    float* __restrict__ out) {
  int wv = threadIdx.x >> 6;
  int lane = threadIdx.x & 63;
  int n = blockIdx.x * 4 + wv;
  __shared__ float lp[4][64];
  __shared__ int   lsrc[4][64];
  int start = offs[n], end = offs[n + 1];
  float aldn = ald[n];
  float M = -INFINITY, S = 0.f, acc = 0.f;
  for (int j0 = start; j0 < end; j0 += 64) {
    int cnt = end - j0; if (cnt > 64) cnt = 64;
    int s = 0; float e = -INFINITY;
    if (lane < cnt) {
      s = esrc[j0 + lane];
      e = als[s] + aldn;
      e = (e > 0.f) ? e : 0.2f * e;               // leaky relu
    }
    float Mn = fmaxf(M, wave_max(e));             // self-loop => cnt>=1
    float scale = __expf(M - Mn);                 // first chunk: exp(-inf)=0
    float p = (lane < cnt) ? __expf(e - Mn) : 0.f;
    S = S * scale + wave_sum(p);
    acc *= scale;
    lp[wv][lane] = p;
    lsrc[wv][lane] = s;                           // wave-local LDS: no barrier
    for (int j = 0; j < cnt; ++j) {               // lanes = channels, 256B coalesced
      acc += lp[wv][j] * hsrc[(size_t)lsrc[wv][j] * 64 + lane];
    }
    M = Mn;
  }
  float v = acc / (S + 1e-16f) + bias[lane];
  out[(size_t)n * 64 + lane] = fmaxf(v, 0.f);
}

// ---------------- fc2 + fc3 + softmax, one wave per batch row ----------------
__global__ __launch_bounds__(256) void fc23_softmax(
    const float* __restrict__ h1, const float* __restrict__ W2,
    const float* __restrict__ b2, const float* __restrict__ W3,
    const float* __restrict__ b3, float* __restrict__ out) {
  int ws = threadIdx.x >> 6;
  int row = blockIdx.x * 4 + ws;
  int lane = threadIdx.x & 63;
  __shared__ float sh2[4][32];
  if (lane < 32) {
    float acc = b2[lane];
    for (int k = 0; k < 64; ++k) acc += h1[row * 64 + k] * W2[k * 32 + lane];
    sh2[ws][lane] = fmaxf(acc, 0.f);
  }
  __syncthreads();
  float logit = -INFINITY;
  if (lane < 16) {
    float acc = b3[lane];
    for (int k = 0; k < 32; ++k) acc += sh2[ws][k] * W3[k * 16 + lane];
    logit = acc;
  }
  float mx = logit;
  #pragma unroll
  for (int o = 8; o >= 1; o >>= 1) mx = fmaxf(mx, __shfl_xor(mx, o));
  float ex = (lane < 16) ? __expf(logit - mx) : 0.f;
  float ssum = ex;
  #pragma unroll
  for (int o = 8; o >= 1; o >>= 1) ssum += __shfl_xor(ssum, o);
  if (lane < 16) out[row * 16 + lane] = ex / ssum;
}

// ---------------- launcher ----------------
extern "C" void kernel_launch(void* const* d_in, const int* in_sizes, int n_in,
                              void* d_out, int out_size, void* d_ws, size_t ws_size,
                              hipStream_t stream) {
  const float* x0   = (const float*)d_in[0];
  const int*   ei   = (const int*)d_in[1];
  const float* W1   = (const float*)d_in[2];
  const float* a1s  = (const float*)d_in[3];
  const float* a1d  = (const float*)d_in[4];
  const float* b1   = (const float*)d_in[5];
  const float* W2   = (const float*)d_in[6];
  const float* a2s  = (const float*)d_in[7];
  const float* a2d  = (const float*)d_in[8];
  const float* b2   = (const float*)d_in[9];
  const float* W3   = (const float*)d_in[10];
  const float* a3s  = (const float*)d_in[11];
  const float* a3d  = (const float*)d_in[12];
  const float* b3   = (const float*)d_in[13];
  const float* fcW1 = (const float*)d_in[14];
  const float* fcb1 = (const float*)d_in[15];
  const float* fcW2 = (const float*)d_in[16];
  const float* fcb2 = (const float*)d_in[17];
  const float* fcW3 = (const float*)d_in[18];
  const float* fcb3 = (const float*)d_in[19];
  float* out = (float*)d_out;

  // workspace layout (~211 MB, matches round-2 footprint)
  float* agg1   = (float*)d_ws;                       // [N*256] 134 MB
  float* h23    = agg1 + (size_t)NN * 256;            // [N*64]  h2, later agg3
  float* agg23  = h23 + (size_t)NN * 64;              // [N*64]  h3
  float* als1   = agg23 + (size_t)NN * 64;            // [N*4]
  float* ald1   = als1 + (size_t)NN * 4;              // [N*4]
  float* als2   = ald1 + (size_t)NN * 4;              // [N]
  float* ald2   = als2 + NN;                          // [N]
  float* wts    = ald2 + NN;                          // [128]
  float* wtd    = wts + 128;                          // [128]
  int*   counts = (int*)(wtd + 128);                  // [N]
  int*   offs   = counts + NN;                        // [N+1]
  int*   cursor = offs + NN + 1;                      // [N]
  int*   esrc   = cursor + NN;                        // [ET]
  int*   blksums= esrc + ET;                          // [512]
  // overlays into agg1 (agg1 is dead after the GAT2 GEMM reads it)
  float* als3   = agg1;                               // [N]
  float* ald3   = agg1 + NN;                          // [N]
  float* hfc1   = agg1 + 2 * (size_t)NN;              // [B*64]

  // CSR build (reused by all 3 GAT layers)
  init_counts<<<NN / 256, 256, 0, stream>>>(counts);
  count_edges<<<EE / 256, 256, 0, stream>>>(ei, counts);
  scan_block<<<NN / 256, 256, 0, stream>>>(counts, offs, blksums);
  scan_sums<<<1, 512, 0, stream>>>(blksums);
  scan_add<<<NN / 256, 256, 0, stream>>>(offs, cursor, blksums);
  fill_csr<<<ET / 256, 256, 0, stream>>>(ei, cursor, esrc);

  // GAT1 in x-space: logits from tiny projections, aggregate x, then W1
  l1_avec<<<1, 128, 0, stream>>>(W1, a1s, a1d, wts, wtd);
  l1_logits<<<NN / 64, 256, 0, stream>>>(x0, wts, wtd, als1, ald1);
  gat1_fused<<<NN / 16, 256, 0, stream>>>(x0, als1, ald1, offs, esrc, W1, b1, agg1);
  // GAT2 GEMM: [N,256]@[256,64] -> h2 + als2/ald2
  gemm_n64<4, 32, true><<<NN / 32, 256, 0, stream>>>(agg1, W2, nullptr, a2s, a2d, h23, als2, ald2);
  // GAT2 aggregate fused with W3 GEMM -> h3 + als3/ald3
  gat_agg_w3<<<NN / 4, 256, 0, stream>>>(h23, als2, ald2, offs, esrc, b2,
                                         W3, a3s, a3d, agg23, als3, ald3);
  // GAT3 aggregate -> agg3 (into h23)
  gat_aggregate<<<NN / 4, 256, 0, stream>>>(agg23, als3, ald3, offs, esrc, b3, h23);
  // actor MLP
  gemm_n64<64, 16, false><<<BB / 16, 256, 0, stream>>>(h23, fcW1, fcb1, nullptr, nullptr, hfc1, nullptr, nullptr);
  fc23_softmax<<<BB / 4, 256, 0, stream>>>(hfc1, fcW2, fcb2, fcW3, fcb3, out);
}